// Round 17
// baseline (395.981 us; speedup 1.0000x reference)
//
#include <hip/hip_runtime.h>
#include <hip/hip_bf16.h>
#include <cstdint>

#define N_NODES 100000
#define N_EDGES 1600000
#define N_GRAPHS 512
#define N_LAYERS 3
#define NB 1563        // ceil(N_NODES/64)
#define BCAP 2048      // per-bucket capacity (mean 1024)
#define NFB 256        // fill blocks (6250 edges each)

typedef __bf16 bf16x8 __attribute__((ext_vector_type(8)));
typedef float f32x4 __attribute__((ext_vector_type(4)));
typedef uint uint4v __attribute__((ext_vector_type(4)));

__device__ __forceinline__ float bf2f(ushort u) {
  uint v = ((uint)u) << 16;
  return __builtin_bit_cast(float, v);
}
__device__ __forceinline__ ushort f2bf(float f) {
  uint u = __builtin_bit_cast(uint, f);
  u += 0x7FFF + ((u >> 16) & 1);   // RNE
  return (ushort)(u >> 16);
}
__device__ __forceinline__ uint pk2(float lo, float hi) {
  return (uint)f2bf(lo) | ((uint)f2bf(hi) << 16);
}

// ---------------- two-pass block-claimed bucket binning ----------------
// int64-vs-int32 detection inlined (thread 0 scans odd words of first 64
// edge values; if all zero the buffer is int64 with small values).
__global__ __launch_bounds__(256) void k_bfill3(const int* __restrict__ e32,
    const long long* __restrict__ e64, int* __restrict__ bcur,
    uint* __restrict__ packed) {
  __shared__ int lcnt[NB];
  __shared__ int lbase[NB];
  __shared__ int sflag;
  const int t = threadIdx.x;
  const int e0 = blockIdx.x * (N_EDGES / NFB);   // 6250 per block
  const int e1 = e0 + (N_EDGES / NFB);
  for (int k = t; k < NB; k += 256) lcnt[k] = 0;
  if (t == 0) {
    int any = 0;
    for (int i = 1; i < 128; i += 2) any |= e32[i];
    sflag = (any == 0) ? 1 : 0;
  }
  __syncthreads();
  const bool f64 = (sflag != 0);
  if (f64) {
    for (int i = e0 + t; i < e1; i += 256)
      atomicAdd(&lcnt[((int)e64[N_EDGES + i]) >> 6], 1);
  } else {
    for (int i = e0 + t; i < e1; i += 256)
      atomicAdd(&lcnt[e32[N_EDGES + i] >> 6], 1);
  }
  __syncthreads();
  for (int k = t; k < NB; k += 256) {
    int c = lcnt[k];
    lbase[k] = (c > 0) ? atomicAdd(&bcur[k * 16], c) : 0;  // padded counters
    lcnt[k] = 0;   // reuse as cursor
  }
  __syncthreads();
  for (int i = e0 + t; i < e1; i += 256) {
    int d, s;
    if (f64) { d = (int)e64[N_EDGES + i]; s = (int)e64[i]; }
    else     { d = e32[N_EDGES + i];      s = e32[i]; }
    int bk = d >> 6;
    int pos = lbase[bk] + atomicAdd(&lcnt[bk], 1);
    if (pos < BCAP)
      packed[(size_t)bk * BCAP + pos] = ((uint)(d & 63) << 17) | (uint)s;
  }
}

// ---------------- per-bucket counting sort -> node-sorted srcs + beg/end ----------------
__global__ __launch_bounds__(256) void k_bsort(const int* __restrict__ bcur,
    const uint* __restrict__ packed, uint* __restrict__ srcs,
    int* __restrict__ nbeg, int* __restrict__ nend) {
  __shared__ uint sp[BCAP];
  __shared__ uint so[BCAP];
  __shared__ int cnt[64], pref[64], cur[64];
  const int bk = blockIdx.x, t = threadIdx.x;
  const int c = min(bcur[bk * 16], BCAP);
  if (t < 64) cnt[t] = 0;
  __syncthreads();
  for (int i = t; i < c; i += 256) {
    uint p = packed[(size_t)bk * BCAP + i];
    sp[i] = p;
    atomicAdd(&cnt[p >> 17], 1);
  }
  __syncthreads();
  if (t == 0) {
    int run = 0;
    #pragma unroll
    for (int j = 0; j < 64; ++j) { pref[j] = run; run += cnt[j]; }
  }
  if (t < 64) cur[t] = 0;
  __syncthreads();
  for (int i = t; i < c; i += 256) {
    uint p = sp[i];
    int n = p >> 17;
    int pos = atomicAdd(&cur[n], 1);
    so[pref[n] + pos] = min(p & 0x1FFFF, (uint)(N_NODES - 1));
  }
  __syncthreads();
  for (int i = t; i < c; i += 256) srcs[(size_t)bk * BCAP + i] = so[i];
  if (t < 64) {
    int base = bk * BCAP;
    nbeg[bk * 64 + t] = base + pref[t];
    nend[bk * 64 + t] = base + pref[t] + cnt[t];
  }
}

// ---------------- prep: weights fp32 -> bf16 transposed Wt[c][k] ----------------
__global__ __launch_bounds__(256) void k_prep_w(const float* __restrict__ W_in,
    const float* __restrict__ W_msg, const float* __restrict__ W_upd,
    ushort* __restrict__ Wt) {
  int b = blockIdx.x;  // 0: in, 1..3: msg[l], 4..6: upd[l]
  const float* W = (b == 0) ? W_in : (b <= 3 ? W_msg + (size_t)(b - 1) * 16384
                                             : W_upd + (size_t)(b - 4) * 16384);
  ushort* O = Wt + (size_t)b * 16384;
  for (int i = threadIdx.x; i < 16384; i += 256) {
    int k = i >> 7, c = i & 127;
    O[c * 128 + k] = f2bf(W[i]);
  }
}

// ---------------- fused bf16 MFMA GEMM (pair / pool) ----------------
// C1 = relu(A@W1+b1)(+res); bf16 C1 stashed in dead sA tile.
// POOL:   in-LDS graph pooling of C1 (last layer; C1 never hits global).
// SECOND: coalesced-store C1 AND reuse the stash as A-operand for
//         C2 = relu(C1@W2+b2) -> out2 (saves one global staging + launch).
// else:   coalesced-store C1 only.
template <bool CVT, bool RES, bool SECOND, bool POOL>
__global__ __launch_bounds__(256) void k_gemm2(const ushort* __restrict__ Ab,
    const float* __restrict__ Af,
    const ushort* __restrict__ W1, const float* __restrict__ b1,
    const ushort* __restrict__ res, ushort* __restrict__ out1,
    const ushort* __restrict__ W2, const float* __restrict__ b2,
    ushort* __restrict__ out2,
    const int* __restrict__ batch, float* __restrict__ g) {
  __shared__ ushort sA[64][136];   // 272B stride -> 2-way bank alias (free)
  __shared__ int sb[64];
  const int t = threadIdx.x;
  const int row0 = blockIdx.x * 64;
  const int lane = t & 63;
  const int col0 = (t >> 6) * 32;
  const int lr = lane & 15, lk = (lane >> 4) * 8;

  // W1 fragments -> registers (L2-broadcast)
  bf16x8 bfr[4][2];
  #pragma unroll
  for (int kk = 0; kk < 4; ++kk) {
    bfr[kk][0] = *(const bf16x8*)&W1[(col0 + lr) * 128 + kk * 32 + lk];
    bfr[kk][1] = *(const bf16x8*)&W1[(col0 + 16 + lr) * 128 + kk * 32 + lk];
  }

  #pragma unroll
  for (int i = 0; i < 4; ++i) {            // A tile: 64 x 128
    int c = t + 256 * i;
    int r = c >> 4, k8 = (c & 15) * 8;
    int gr = min(row0 + r, N_NODES - 1);
    if (CVT) {
      const float* src = &Af[(size_t)gr * 128 + k8];
      float4 x0 = *(const float4*)src;
      float4 x1 = *(const float4*)(src + 4);
      uint4v u;
      u.x = pk2(x0.x, x0.y); u.y = pk2(x0.z, x0.w);
      u.z = pk2(x1.x, x1.y); u.w = pk2(x1.z, x1.w);
      *(uint4v*)&sA[r][k8] = u;
    } else {
      *(uint4*)&sA[r][k8] = *(const uint4*)&Ab[(size_t)gr * 128 + k8];
    }
  }
  __syncthreads();

  f32x4 acc[4][2] = {};
  #pragma unroll
  for (int kk = 0; kk < 4; ++kk) {
    int kb = kk * 32 + lk;
    #pragma unroll
    for (int m = 0; m < 4; ++m) {
      bf16x8 a = *(const bf16x8*)&sA[m * 16 + lr][kb];
      acc[m][0] = __builtin_amdgcn_mfma_f32_16x16x32_bf16(a, bfr[kk][0], acc[m][0], 0, 0, 0);
      acc[m][1] = __builtin_amdgcn_mfma_f32_16x16x32_bf16(a, bfr[kk][1], acc[m][1], 0, 0, 0);
    }
  }

  // W2 fragments (issued while waiting on the barrier)
  bf16x8 bfr2[4][2];
  if (SECOND) {
    #pragma unroll
    for (int kk = 0; kk < 4; ++kk) {
      bfr2[kk][0] = *(const bf16x8*)&W2[(col0 + lr) * 128 + kk * 32 + lk];
      bfr2[kk][1] = *(const bf16x8*)&W2[(col0 + 16 + lr) * 128 + kk * 32 + lk];
    }
  }
  __syncthreads();   // all sA reads done before stash

  const int rb = (lane >> 4) * 4;   // C/D: row=(lane>>4)*4+j, col=lane&15
  #pragma unroll
  for (int n = 0; n < 2; ++n) {
    int col = col0 + n * 16 + lr;
    float bv = b1[col];
    #pragma unroll
    for (int m = 0; m < 4; ++m) {
      #pragma unroll
      for (int j = 0; j < 4; ++j) {
        int r = row0 + m * 16 + rb + j;
        float v = fmaxf(acc[m][n][j] + bv, 0.f);
        if (RES && r < N_NODES) v += bf2f(res[(size_t)r * 128 + col]);
        sA[m * 16 + rb + j][col] = f2bf(v);
      }
    }
  }
  if (POOL && t < 64)
    sb[t] = (row0 + t < N_NODES) ? batch[row0 + t] : -1;
  __syncthreads();

  if (POOL) {
    // column-scan pooling: thread handles col (t&127), rows [half*32, +32)
    int c = t & 127, half = t >> 7;
    int v0 = half * 32, v1 = v0 + 32;
    int cur = sb[v0];
    if (cur >= 0) {
      float acc2 = 0.f;
      for (int v = v0; v < v1; ++v) {
        int b = sb[v];
        if (b < 0) break;
        if (b != cur) {
          unsafeAtomicAdd(&g[cur * 128 + c], acc2);
          acc2 = 0.f;
          cur = b;
        }
        acc2 += bf2f(sA[v][c]);
      }
      unsafeAtomicAdd(&g[cur * 128 + c], acc2);
    }
    return;
  }

  #pragma unroll
  for (int i = 0; i < 4; ++i) {            // coalesced 16B stores of C1
    int c = t + 256 * i;
    int r = c >> 4, k8 = (c & 15) * 8;
    int gr = row0 + r;
    if (gr < N_NODES)
      *(uint4*)&out1[(size_t)gr * 128 + k8] = *(const uint4*)&sA[r][k8];
  }

  if (SECOND) {
    // second GEMM: A-operand = stashed C1 (read-only on sA, no barrier vs stores)
    f32x4 acc2[4][2] = {};
    #pragma unroll
    for (int kk = 0; kk < 4; ++kk) {
      int kb = kk * 32 + lk;
      #pragma unroll
      for (int m = 0; m < 4; ++m) {
        bf16x8 a = *(const bf16x8*)&sA[m * 16 + lr][kb];
        acc2[m][0] = __builtin_amdgcn_mfma_f32_16x16x32_bf16(a, bfr2[kk][0], acc2[m][0], 0, 0, 0);
        acc2[m][1] = __builtin_amdgcn_mfma_f32_16x16x32_bf16(a, bfr2[kk][1], acc2[m][1], 0, 0, 0);
      }
    }
    __syncthreads();   // MFMA2 reads + C1 stores done before re-stash

    #pragma unroll
    for (int n = 0; n < 2; ++n) {
      int col = col0 + n * 16 + lr;
      float bv = b2[col];
      #pragma unroll
      for (int m = 0; m < 4; ++m) {
        #pragma unroll
        for (int j = 0; j < 4; ++j) {
          float v = fmaxf(acc2[m][n][j] + bv, 0.f);
          sA[m * 16 + rb + j][col] = f2bf(v);
        }
      }
    }
    __syncthreads();

    #pragma unroll
    for (int i = 0; i < 4; ++i) {          // coalesced 16B stores of C2
      int c = t + 256 * i;
      int r = c >> 4, k8 = (c & 15) * 8;
      int gr = row0 + r;
      if (gr < N_NODES)
        *(uint4*)&out2[(size_t)gr * 128 + k8] = *(const uint4*)&sA[r][k8];
    }
  }
}

// ---------------- aggregation: one wave per node, 16 edges in flight ----------------
__global__ __launch_bounds__(256) void k_aggregate(const int* __restrict__ nbeg,
    const int* __restrict__ nend, const uint* __restrict__ srcs,
    const ushort* __restrict__ msg, ushort* __restrict__ agg) {
  int wid = blockIdx.x * 4 + (threadIdx.x >> 6);
  if (wid >= N_NODES) return;
  const int lane = threadIdx.x & 63;
  const uint sub = lane >> 4, l16 = lane & 15;
  int e = nbeg[wid];
  const int en = nend[wid];
  float a[8] = {0.f, 0.f, 0.f, 0.f, 0.f, 0.f, 0.f, 0.f};

#define ACC8(mv)                                              \
  a[0] += bf2f((ushort)mv.x); a[1] += bf2f((ushort)(mv.x >> 16)); \
  a[2] += bf2f((ushort)mv.y); a[3] += bf2f((ushort)(mv.y >> 16)); \
  a[4] += bf2f((ushort)mv.z); a[5] += bf2f((ushort)(mv.z >> 16)); \
  a[6] += bf2f((ushort)mv.w); a[7] += bf2f((ushort)(mv.w >> 16));

  for (; e + 16 <= en; e += 16) {
    uint s0 = srcs[e + sub];
    uint s1 = srcs[e + 4 + sub];
    uint s2 = srcs[e + 8 + sub];
    uint s3 = srcs[e + 12 + sub];
    uint4 m0 = *(const uint4*)&msg[s0 * 128u + l16 * 8u];
    uint4 m1 = *(const uint4*)&msg[s1 * 128u + l16 * 8u];
    uint4 m2 = *(const uint4*)&msg[s2 * 128u + l16 * 8u];
    uint4 m3 = *(const uint4*)&msg[s3 * 128u + l16 * 8u];
    ACC8(m0) ACC8(m1) ACC8(m2) ACC8(m3)
  }
  const uint rem = (uint)(en - e);   // 0..15
  #pragma unroll
  for (uint k = 0; k < 4; ++k) {
    uint idx = k * 4 + sub;
    if (idx < rem) {
      uint s = srcs[e + idx];
      uint4 m = *(const uint4*)&msg[s * 128u + l16 * 8u];
      ACC8(m)
    }
  }
#undef ACC8

  #pragma unroll
  for (int j = 0; j < 8; ++j) {
    a[j] += __shfl_xor(a[j], 16, 64);
    a[j] += __shfl_xor(a[j], 32, 64);
  }
  if (sub == 0) {
    uint4 r;
    r.x = pk2(a[0], a[1]);
    r.y = pk2(a[2], a[3]);
    r.z = pk2(a[4], a[5]);
    r.w = pk2(a[6], a[7]);
    *(uint4*)&agg[(size_t)wid * 128 + l16 * 8] = r;
  }
}

// ---------------- output heads (fp32) ----------------
__global__ __launch_bounds__(128) void k_head(const float* __restrict__ g,
    const float* __restrict__ Wm, const float* __restrict__ bm,
    const float* __restrict__ Wl, const float* __restrict__ bl,
    float* __restrict__ out) {
  __shared__ float sg[128];
  int gr = blockIdx.x, t = threadIdx.x;
  sg[t] = g[gr * 128 + t];
  __syncthreads();
  const float* W = (t < 64) ? Wm : Wl;
  const float* b = (t < 64) ? bm : bl;
  int c = t & 63;
  float acc = b[c];
  #pragma unroll 8
  for (int k = 0; k < 128; ++k) acc += sg[k] * W[k * 64 + c];
  out[(size_t)(t < 64 ? 0 : N_GRAPHS * 64) + (size_t)gr * 64 + c] = acc;
}

// ---------------- host ----------------
extern "C" void kernel_launch(void* const* d_in, const int* in_sizes, int n_in,
                              void* d_out, int out_size, void* d_ws, size_t ws_size,
                              hipStream_t stream) {
  const float* x      = (const float*)d_in[0];
  const int* e32      = (const int*)d_in[1];
  const long long* e64 = (const long long*)d_in[1];
  const int* batch    = (const int*)d_in[2];
  const float* W_in   = (const float*)d_in[3];
  const float* b_in   = (const float*)d_in[4];
  const float* W_msg  = (const float*)d_in[5];
  const float* b_msg  = (const float*)d_in[6];
  const float* W_upd  = (const float*)d_in[7];
  const float* b_upd  = (const float*)d_in[8];
  const float* W_mean = (const float*)d_in[9];
  const float* b_mean = (const float*)d_in[10];
  const float* W_lv   = (const float*)d_in[11];
  const float* b_lv   = (const float*)d_in[12];
  float* out = (float*)d_out;

  char* p = (char*)d_ws;
  auto alloc = [&](size_t bytes) {
    char* r = p;
    p += (bytes + 255) & ~(size_t)255;
    return r;
  };
  ushort* bufA   = (ushort*)alloc((size_t)N_NODES * 128 * 2);
  ushort* bufB   = (ushort*)alloc((size_t)N_NODES * 128 * 2);
  ushort* bufC   = (ushort*)alloc((size_t)N_NODES * 128 * 2);
  ushort* bufM   = (ushort*)alloc((size_t)N_NODES * 128 * 2);
  ushort* Wt     = (ushort*)alloc((size_t)7 * 16384 * 2);
  uint*   packed = (uint*)alloc((size_t)NB * BCAP * 4);
  uint*   srcs   = (uint*)alloc((size_t)NB * BCAP * 4);
  int*    bcur   = (int*)alloc((size_t)NB * 16 * 4);
  int*    nbeg   = (int*)alloc((size_t)NB * 64 * 4);
  int*    nend   = (int*)alloc((size_t)NB * 64 * 4);
  float*  g      = (float*)alloc((size_t)N_GRAPHS * 128 * 4);

  hipMemsetAsync(bcur, 0, (size_t)NB * 16 * 4, stream);
  hipMemsetAsync(g, 0, (size_t)N_GRAPHS * 128 * 4, stream);

  // CSR build (two-pass claimed binning, dtype detect inlined)
  k_bfill3<<<NFB, 256, 0, stream>>>(e32, e64, bcur, packed);
  k_bsort<<<NB, 256, 0, stream>>>(bcur, packed, srcs, nbeg, nend);

  // weight prep
  k_prep_w<<<7, 256, 0, stream>>>(W_in, W_msg, W_upd, Wt);

  const int GB = NB;  // 64-row GEMM blocks
  const ushort* Wm[3] = {Wt + 16384, Wt + 2 * 16384, Wt + 3 * 16384};
  const ushort* Wu[3] = {Wt + 4 * 16384, Wt + 5 * 16384, Wt + 6 * 16384};

  // fused: h0 = relu(x@W_in+b_in) ; msg0 = relu(h0@Wm0+bm0)
  k_gemm2<true, false, true, false><<<GB, 256, 0, stream>>>(
      nullptr, x, Wt, b_in, nullptr, bufA, Wm[0], b_msg, bufM, nullptr, nullptr);

  ushort* h = bufA;
  ushort* hn = bufB;
  for (int l = 0; l < N_LAYERS; ++l) {
    k_aggregate<<<(N_NODES + 3) / 4, 256, 0, stream>>>(nbeg, nend, srcs, bufM, bufC);
    if (l < N_LAYERS - 1) {
      // fused: hn = relu(agg@Wu+bu)+h ; msg_{l+1} = relu(hn@Wm+bm)
      k_gemm2<false, true, true, false><<<GB, 256, 0, stream>>>(
          bufC, nullptr, Wu[l], b_upd + (size_t)l * 128, h, hn,
          Wm[l + 1], b_msg + (size_t)(l + 1) * 128, bufM, nullptr, nullptr);
      ushort* sw = h; h = hn; hn = sw;
    } else {
      // last layer: pool fused, h3 never hits global memory
      k_gemm2<false, true, false, true><<<GB, 256, 0, stream>>>(
          bufC, nullptr, Wu[l], b_upd + (size_t)l * 128, h, nullptr,
          nullptr, nullptr, nullptr, batch, g);
    }
  }

  // heads
  k_head<<<N_GRAPHS, 128, 0, stream>>>(g, W_mean, b_mean, W_lv, b_lv, out);
}

// Round 18
// 389.329 us; speedup vs baseline: 1.0171x; 1.0171x over previous
//
#include <hip/hip_runtime.h>
#include <hip/hip_bf16.h>
#include <cstdint>

#define N_NODES 100000
#define N_EDGES 1600000
#define N_GRAPHS 512
#define N_LAYERS 3
#define NB 1563        // ceil(N_NODES/64)
#define BCAP 2048      // per-bucket capacity (mean 1024)
#define NFB 256        // fill blocks (6250 edges each)

typedef __bf16 bf16x8 __attribute__((ext_vector_type(8)));
typedef float f32x4 __attribute__((ext_vector_type(4)));
typedef uint uint4v __attribute__((ext_vector_type(4)));

__device__ __forceinline__ float bf2f(ushort u) {
  uint v = ((uint)u) << 16;
  return __builtin_bit_cast(float, v);
}
__device__ __forceinline__ ushort f2bf(float f) {
  uint u = __builtin_bit_cast(uint, f);
  u += 0x7FFF + ((u >> 16) & 1);   // RNE
  return (ushort)(u >> 16);
}
__device__ __forceinline__ uint pk2(float lo, float hi) {
  return (uint)f2bf(lo) | ((uint)f2bf(hi) << 16);
}

// ---------------- two-pass block-claimed bucket binning ----------------
// 1024 threads (16 waves/block, 2 blocks/CU): k_bfill3 was latency-bound at
// 4 waves/CU (R17: occupancy 9.4%, VALUBusy 1.5%) — more waves hide the
// scattered-store + claim latency. Grid stays 256 so claim count unchanged.
__global__ __launch_bounds__(1024) void k_bfill3(const int* __restrict__ e32,
    const long long* __restrict__ e64, int* __restrict__ bcur,
    uint* __restrict__ packed) {
  __shared__ int lcnt[NB];
  __shared__ int lbase[NB];
  __shared__ int sflag;
  const int t = threadIdx.x;
  const int e0 = blockIdx.x * (N_EDGES / NFB);   // 6250 per block
  const int e1 = e0 + (N_EDGES / NFB);
  for (int k = t; k < NB; k += 1024) lcnt[k] = 0;
  if (t == 0) {
    int any = 0;
    for (int i = 1; i < 128; i += 2) any |= e32[i];
    sflag = (any == 0) ? 1 : 0;
  }
  __syncthreads();
  const bool f64 = (sflag != 0);
  if (f64) {
    for (int i = e0 + t; i < e1; i += 1024)
      atomicAdd(&lcnt[((int)e64[N_EDGES + i]) >> 6], 1);
  } else {
    for (int i = e0 + t; i < e1; i += 1024)
      atomicAdd(&lcnt[e32[N_EDGES + i] >> 6], 1);
  }
  __syncthreads();
  for (int k = t; k < NB; k += 1024) {
    int c = lcnt[k];
    lbase[k] = (c > 0) ? atomicAdd(&bcur[k * 16], c) : 0;  // padded counters
    lcnt[k] = 0;   // reuse as cursor
  }
  __syncthreads();
  for (int i = e0 + t; i < e1; i += 1024) {
    int d, s;
    if (f64) { d = (int)e64[N_EDGES + i]; s = (int)e64[i]; }
    else     { d = e32[N_EDGES + i];      s = e32[i]; }
    int bk = d >> 6;
    int pos = lbase[bk] + atomicAdd(&lcnt[bk], 1);
    if (pos < BCAP)
      packed[(size_t)bk * BCAP + pos] = ((uint)(d & 63) << 17) | (uint)s;
  }
}

// ---------------- per-bucket counting sort -> node-sorted srcs + beg/end ----------------
__global__ __launch_bounds__(256) void k_bsort(const int* __restrict__ bcur,
    const uint* __restrict__ packed, uint* __restrict__ srcs,
    int* __restrict__ nbeg, int* __restrict__ nend) {
  __shared__ uint sp[BCAP];
  __shared__ uint so[BCAP];
  __shared__ int cnt[64], pref[64], cur[64];
  const int bk = blockIdx.x, t = threadIdx.x;
  const int c = min(bcur[bk * 16], BCAP);
  if (t < 64) cnt[t] = 0;
  __syncthreads();
  for (int i = t; i < c; i += 256) {
    uint p = packed[(size_t)bk * BCAP + i];
    sp[i] = p;
    atomicAdd(&cnt[p >> 17], 1);
  }
  __syncthreads();
  if (t == 0) {
    int run = 0;
    #pragma unroll
    for (int j = 0; j < 64; ++j) { pref[j] = run; run += cnt[j]; }
  }
  if (t < 64) cur[t] = 0;
  __syncthreads();
  for (int i = t; i < c; i += 256) {
    uint p = sp[i];
    int n = p >> 17;
    int pos = atomicAdd(&cur[n], 1);
    so[pref[n] + pos] = min(p & 0x1FFFF, (uint)(N_NODES - 1));
  }
  __syncthreads();
  for (int i = t; i < c; i += 256) srcs[(size_t)bk * BCAP + i] = so[i];
  if (t < 64) {
    int base = bk * BCAP;
    nbeg[bk * 64 + t] = base + pref[t];
    nend[bk * 64 + t] = base + pref[t] + cnt[t];
  }
}

// ---------------- prep: weights fp32 -> bf16 transposed Wt[c][k] ----------------
__global__ __launch_bounds__(256) void k_prep_w(const float* __restrict__ W_in,
    const float* __restrict__ W_msg, const float* __restrict__ W_upd,
    ushort* __restrict__ Wt) {
  int b = blockIdx.x;  // 0: in, 1..3: msg[l], 4..6: upd[l]
  const float* W = (b == 0) ? W_in : (b <= 3 ? W_msg + (size_t)(b - 1) * 16384
                                             : W_upd + (size_t)(b - 4) * 16384);
  ushort* O = Wt + (size_t)b * 16384;
  for (int i = threadIdx.x; i < 16384; i += 256) {
    int k = i >> 7, c = i & 127;
    O[c * 128 + k] = f2bf(W[i]);
  }
}

// ---------------- fused bf16 MFMA GEMM (pair / pool) ----------------
// C1 = relu(A@W1+b1)(+res); bf16 C1 stashed in dead sA tile.
// POOL:   in-LDS graph pooling of C1 (last layer; C1 never hits global).
// SECOND: coalesced-store C1 AND reuse the stash as A-operand for
//         C2 = relu(C1@W2+b2) -> out2 (saves one global staging + launch).
// else:   coalesced-store C1 only.
template <bool CVT, bool RES, bool SECOND, bool POOL>
__global__ __launch_bounds__(256) void k_gemm2(const ushort* __restrict__ Ab,
    const float* __restrict__ Af,
    const ushort* __restrict__ W1, const float* __restrict__ b1,
    const ushort* __restrict__ res, ushort* __restrict__ out1,
    const ushort* __restrict__ W2, const float* __restrict__ b2,
    ushort* __restrict__ out2,
    const int* __restrict__ batch, float* __restrict__ g) {
  __shared__ ushort sA[64][136];   // 272B stride -> 2-way bank alias (free)
  __shared__ int sb[64];
  const int t = threadIdx.x;
  const int row0 = blockIdx.x * 64;
  const int lane = t & 63;
  const int col0 = (t >> 6) * 32;
  const int lr = lane & 15, lk = (lane >> 4) * 8;

  // W1 fragments -> registers (L2-broadcast)
  bf16x8 bfr[4][2];
  #pragma unroll
  for (int kk = 0; kk < 4; ++kk) {
    bfr[kk][0] = *(const bf16x8*)&W1[(col0 + lr) * 128 + kk * 32 + lk];
    bfr[kk][1] = *(const bf16x8*)&W1[(col0 + 16 + lr) * 128 + kk * 32 + lk];
  }

  #pragma unroll
  for (int i = 0; i < 4; ++i) {            // A tile: 64 x 128
    int c = t + 256 * i;
    int r = c >> 4, k8 = (c & 15) * 8;
    int gr = min(row0 + r, N_NODES - 1);
    if (CVT) {
      const float* src = &Af[(size_t)gr * 128 + k8];
      float4 x0 = *(const float4*)src;
      float4 x1 = *(const float4*)(src + 4);
      uint4v u;
      u.x = pk2(x0.x, x0.y); u.y = pk2(x0.z, x0.w);
      u.z = pk2(x1.x, x1.y); u.w = pk2(x1.z, x1.w);
      *(uint4v*)&sA[r][k8] = u;
    } else {
      *(uint4*)&sA[r][k8] = *(const uint4*)&Ab[(size_t)gr * 128 + k8];
    }
  }
  __syncthreads();

  f32x4 acc[4][2] = {};
  #pragma unroll
  for (int kk = 0; kk < 4; ++kk) {
    int kb = kk * 32 + lk;
    #pragma unroll
    for (int m = 0; m < 4; ++m) {
      bf16x8 a = *(const bf16x8*)&sA[m * 16 + lr][kb];
      acc[m][0] = __builtin_amdgcn_mfma_f32_16x16x32_bf16(a, bfr[kk][0], acc[m][0], 0, 0, 0);
      acc[m][1] = __builtin_amdgcn_mfma_f32_16x16x32_bf16(a, bfr[kk][1], acc[m][1], 0, 0, 0);
    }
  }

  // W2 fragments (issued while waiting on the barrier)
  bf16x8 bfr2[4][2];
  if (SECOND) {
    #pragma unroll
    for (int kk = 0; kk < 4; ++kk) {
      bfr2[kk][0] = *(const bf16x8*)&W2[(col0 + lr) * 128 + kk * 32 + lk];
      bfr2[kk][1] = *(const bf16x8*)&W2[(col0 + 16 + lr) * 128 + kk * 32 + lk];
    }
  }
  __syncthreads();   // all sA reads done before stash

  const int rb = (lane >> 4) * 4;   // C/D: row=(lane>>4)*4+j, col=lane&15
  #pragma unroll
  for (int n = 0; n < 2; ++n) {
    int col = col0 + n * 16 + lr;
    float bv = b1[col];
    #pragma unroll
    for (int m = 0; m < 4; ++m) {
      #pragma unroll
      for (int j = 0; j < 4; ++j) {
        int r = row0 + m * 16 + rb + j;
        float v = fmaxf(acc[m][n][j] + bv, 0.f);
        if (RES && r < N_NODES) v += bf2f(res[(size_t)r * 128 + col]);
        sA[m * 16 + rb + j][col] = f2bf(v);
      }
    }
  }
  if (POOL && t < 64)
    sb[t] = (row0 + t < N_NODES) ? batch[row0 + t] : -1;
  __syncthreads();

  if (POOL) {
    // column-scan pooling: thread handles col (t&127), rows [half*32, +32)
    int c = t & 127, half = t >> 7;
    int v0 = half * 32, v1 = v0 + 32;
    int cur = sb[v0];
    if (cur >= 0) {
      float acc2 = 0.f;
      for (int v = v0; v < v1; ++v) {
        int b = sb[v];
        if (b < 0) break;
        if (b != cur) {
          unsafeAtomicAdd(&g[cur * 128 + c], acc2);
          acc2 = 0.f;
          cur = b;
        }
        acc2 += bf2f(sA[v][c]);
      }
      unsafeAtomicAdd(&g[cur * 128 + c], acc2);
    }
    return;
  }

  #pragma unroll
  for (int i = 0; i < 4; ++i) {            // coalesced 16B stores of C1
    int c = t + 256 * i;
    int r = c >> 4, k8 = (c & 15) * 8;
    int gr = row0 + r;
    if (gr < N_NODES)
      *(uint4*)&out1[(size_t)gr * 128 + k8] = *(const uint4*)&sA[r][k8];
  }

  if (SECOND) {
    // second GEMM: A-operand = stashed C1 (read-only on sA, no barrier vs stores)
    f32x4 acc2[4][2] = {};
    #pragma unroll
    for (int kk = 0; kk < 4; ++kk) {
      int kb = kk * 32 + lk;
      #pragma unroll
      for (int m = 0; m < 4; ++m) {
        bf16x8 a = *(const bf16x8*)&sA[m * 16 + lr][kb];
        acc2[m][0] = __builtin_amdgcn_mfma_f32_16x16x32_bf16(a, bfr2[kk][0], acc2[m][0], 0, 0, 0);
        acc2[m][1] = __builtin_amdgcn_mfma_f32_16x16x32_bf16(a, bfr2[kk][1], acc2[m][1], 0, 0, 0);
      }
    }
    __syncthreads();   // MFMA2 reads + C1 stores done before re-stash

    #pragma unroll
    for (int n = 0; n < 2; ++n) {
      int col = col0 + n * 16 + lr;
      float bv = b2[col];
      #pragma unroll
      for (int m = 0; m < 4; ++m) {
        #pragma unroll
        for (int j = 0; j < 4; ++j) {
          float v = fmaxf(acc2[m][n][j] + bv, 0.f);
          sA[m * 16 + rb + j][col] = f2bf(v);
        }
      }
    }
    __syncthreads();

    #pragma unroll
    for (int i = 0; i < 4; ++i) {          // coalesced 16B stores of C2
      int c = t + 256 * i;
      int r = c >> 4, k8 = (c & 15) * 8;
      int gr = row0 + r;
      if (gr < N_NODES)
        *(uint4*)&out2[(size_t)gr * 128 + k8] = *(const uint4*)&sA[r][k8];
    }
  }
}

// ---------------- aggregation: one wave per node, 16 edges in flight ----------------
__global__ __launch_bounds__(256) void k_aggregate(const int* __restrict__ nbeg,
    const int* __restrict__ nend, const uint* __restrict__ srcs,
    const ushort* __restrict__ msg, ushort* __restrict__ agg) {
  int wid = blockIdx.x * 4 + (threadIdx.x >> 6);
  if (wid >= N_NODES) return;
  const int lane = threadIdx.x & 63;
  const uint sub = lane >> 4, l16 = lane & 15;
  int e = nbeg[wid];
  const int en = nend[wid];
  float a[8] = {0.f, 0.f, 0.f, 0.f, 0.f, 0.f, 0.f, 0.f};

#define ACC8(mv)                                              \
  a[0] += bf2f((ushort)mv.x); a[1] += bf2f((ushort)(mv.x >> 16)); \
  a[2] += bf2f((ushort)mv.y); a[3] += bf2f((ushort)(mv.y >> 16)); \
  a[4] += bf2f((ushort)mv.z); a[5] += bf2f((ushort)(mv.z >> 16)); \
  a[6] += bf2f((ushort)mv.w); a[7] += bf2f((ushort)(mv.w >> 16));

  for (; e + 16 <= en; e += 16) {
    uint s0 = srcs[e + sub];
    uint s1 = srcs[e + 4 + sub];
    uint s2 = srcs[e + 8 + sub];
    uint s3 = srcs[e + 12 + sub];
    uint4 m0 = *(const uint4*)&msg[s0 * 128u + l16 * 8u];
    uint4 m1 = *(const uint4*)&msg[s1 * 128u + l16 * 8u];
    uint4 m2 = *(const uint4*)&msg[s2 * 128u + l16 * 8u];
    uint4 m3 = *(const uint4*)&msg[s3 * 128u + l16 * 8u];
    ACC8(m0) ACC8(m1) ACC8(m2) ACC8(m3)
  }
  const uint rem = (uint)(en - e);   // 0..15
  #pragma unroll
  for (uint k = 0; k < 4; ++k) {
    uint idx = k * 4 + sub;
    if (idx < rem) {
      uint s = srcs[e + idx];
      uint4 m = *(const uint4*)&msg[s * 128u + l16 * 8u];
      ACC8(m)
    }
  }
#undef ACC8

  #pragma unroll
  for (int j = 0; j < 8; ++j) {
    a[j] += __shfl_xor(a[j], 16, 64);
    a[j] += __shfl_xor(a[j], 32, 64);
  }
  if (sub == 0) {
    uint4 r;
    r.x = pk2(a[0], a[1]);
    r.y = pk2(a[2], a[3]);
    r.z = pk2(a[4], a[5]);
    r.w = pk2(a[6], a[7]);
    *(uint4*)&agg[(size_t)wid * 128 + l16 * 8] = r;
  }
}

// ---------------- output heads (fp32) ----------------
__global__ __launch_bounds__(128) void k_head(const float* __restrict__ g,
    const float* __restrict__ Wm, const float* __restrict__ bm,
    const float* __restrict__ Wl, const float* __restrict__ bl,
    float* __restrict__ out) {
  __shared__ float sg[128];
  int gr = blockIdx.x, t = threadIdx.x;
  sg[t] = g[gr * 128 + t];
  __syncthreads();
  const float* W = (t < 64) ? Wm : Wl;
  const float* b = (t < 64) ? bm : bl;
  int c = t & 63;
  float acc = b[c];
  #pragma unroll 8
  for (int k = 0; k < 128; ++k) acc += sg[k] * W[k * 64 + c];
  out[(size_t)(t < 64 ? 0 : N_GRAPHS * 64) + (size_t)gr * 64 + c] = acc;
}

// ---------------- host ----------------
extern "C" void kernel_launch(void* const* d_in, const int* in_sizes, int n_in,
                              void* d_out, int out_size, void* d_ws, size_t ws_size,
                              hipStream_t stream) {
  const float* x      = (const float*)d_in[0];
  const int* e32      = (const int*)d_in[1];
  const long long* e64 = (const long long*)d_in[1];
  const int* batch    = (const int*)d_in[2];
  const float* W_in   = (const float*)d_in[3];
  const float* b_in   = (const float*)d_in[4];
  const float* W_msg  = (const float*)d_in[5];
  const float* b_msg  = (const float*)d_in[6];
  const float* W_upd  = (const float*)d_in[7];
  const float* b_upd  = (const float*)d_in[8];
  const float* W_mean = (const float*)d_in[9];
  const float* b_mean = (const float*)d_in[10];
  const float* W_lv   = (const float*)d_in[11];
  const float* b_lv   = (const float*)d_in[12];
  float* out = (float*)d_out;

  char* p = (char*)d_ws;
  auto alloc = [&](size_t bytes) {
    char* r = p;
    p += (bytes + 255) & ~(size_t)255;
    return r;
  };
  ushort* bufA   = (ushort*)alloc((size_t)N_NODES * 128 * 2);
  ushort* bufB   = (ushort*)alloc((size_t)N_NODES * 128 * 2);
  ushort* bufC   = (ushort*)alloc((size_t)N_NODES * 128 * 2);
  ushort* bufM   = (ushort*)alloc((size_t)N_NODES * 128 * 2);
  ushort* Wt     = (ushort*)alloc((size_t)7 * 16384 * 2);
  uint*   packed = (uint*)alloc((size_t)NB * BCAP * 4);
  uint*   srcs   = (uint*)alloc((size_t)NB * BCAP * 4);
  int*    bcur   = (int*)alloc((size_t)NB * 16 * 4);
  int*    nbeg   = (int*)alloc((size_t)NB * 64 * 4);
  int*    nend   = (int*)alloc((size_t)NB * 64 * 4);
  float*  g      = (float*)alloc((size_t)N_GRAPHS * 128 * 4);

  hipMemsetAsync(bcur, 0, (size_t)NB * 16 * 4, stream);
  hipMemsetAsync(g, 0, (size_t)N_GRAPHS * 128 * 4, stream);

  // CSR build (two-pass claimed binning, dtype detect inlined)
  k_bfill3<<<NFB, 1024, 0, stream>>>(e32, e64, bcur, packed);
  k_bsort<<<NB, 256, 0, stream>>>(bcur, packed, srcs, nbeg, nend);

  // weight prep
  k_prep_w<<<7, 256, 0, stream>>>(W_in, W_msg, W_upd, Wt);

  const int GB = NB;  // 64-row GEMM blocks
  const ushort* Wm[3] = {Wt + 16384, Wt + 2 * 16384, Wt + 3 * 16384};
  const ushort* Wu[3] = {Wt + 4 * 16384, Wt + 5 * 16384, Wt + 6 * 16384};

  // fused: h0 = relu(x@W_in+b_in) ; msg0 = relu(h0@Wm0+bm0)
  k_gemm2<true, false, true, false><<<GB, 256, 0, stream>>>(
      nullptr, x, Wt, b_in, nullptr, bufA, Wm[0], b_msg, bufM, nullptr, nullptr);

  ushort* h = bufA;
  ushort* hn = bufB;
  for (int l = 0; l < N_LAYERS; ++l) {
    k_aggregate<<<(N_NODES + 3) / 4, 256, 0, stream>>>(nbeg, nend, srcs, bufM, bufC);
    if (l < N_LAYERS - 1) {
      // fused: hn = relu(agg@Wu+bu)+h ; msg_{l+1} = relu(hn@Wm+bm)
      k_gemm2<false, true, true, false><<<GB, 256, 0, stream>>>(
          bufC, nullptr, Wu[l], b_upd + (size_t)l * 128, h, hn,
          Wm[l + 1], b_msg + (size_t)(l + 1) * 128, bufM, nullptr, nullptr);
      ushort* sw = h; h = hn; hn = sw;
    } else {
      // last layer: pool fused, h3 never hits global memory
      k_gemm2<false, true, false, true><<<GB, 256, 0, stream>>>(
          bufC, nullptr, Wu[l], b_upd + (size_t)l * 128, h, nullptr,
          nullptr, nullptr, nullptr, batch, g);
    }
  }

  // heads
  k_head<<<N_GRAPHS, 128, 0, stream>>>(g, W_mean, b_mean, W_lv, b_lv, out);
}

// Round 19
// 385.069 us; speedup vs baseline: 1.0283x; 1.0111x over previous
//
#include <hip/hip_runtime.h>
#include <hip/hip_bf16.h>
#include <cstdint>

#define N_NODES 100000
#define N_EDGES 1600000
#define N_GRAPHS 512
#define N_LAYERS 3
#define NB 1563        // ceil(N_NODES/64)
#define BCAP 2048      // per-bucket capacity (mean 1024)
#define NFB 256        // fill blocks (6250 edges each)

typedef __bf16 bf16x8 __attribute__((ext_vector_type(8)));
typedef float f32x4 __attribute__((ext_vector_type(4)));
typedef uint uint4v __attribute__((ext_vector_type(4)));

__device__ __forceinline__ float bf2f(ushort u) {
  uint v = ((uint)u) << 16;
  return __builtin_bit_cast(float, v);
}
__device__ __forceinline__ ushort f2bf(float f) {
  uint u = __builtin_bit_cast(uint, f);
  u += 0x7FFF + ((u >> 16) & 1);   // RNE
  return (ushort)(u >> 16);
}
__device__ __forceinline__ uint pk2(float lo, float hi) {
  return (uint)f2bf(lo) | ((uint)f2bf(hi) << 16);
}

// shared-memory layouts (union'd in fat kernels)
struct BsortSh {
  uint sp[BCAP];
  uint so[BCAP];
  int cnt[64], pref[64], cur[64];
};
struct GemmSh {
  ushort sA[64][136];   // 272B stride -> 2-way bank alias (free)
  int sb[64];
};
union FatSh {
  BsortSh b;
  GemmSh g;
};

// ---------------- bsort body: per-bucket counting sort ----------------
__device__ __forceinline__ void bsort_body(BsortSh& S, int bk, int t,
    const int* __restrict__ bcur, const uint* __restrict__ packed,
    uint* __restrict__ srcs, int* __restrict__ nbeg, int* __restrict__ nend) {
  const int c = min(bcur[bk * 16], BCAP);
  if (t < 64) S.cnt[t] = 0;
  __syncthreads();
  for (int i = t; i < c; i += 256) {
    uint p = packed[(size_t)bk * BCAP + i];
    S.sp[i] = p;
    atomicAdd(&S.cnt[p >> 17], 1);
  }
  __syncthreads();
  if (t == 0) {
    int run = 0;
    #pragma unroll
    for (int j = 0; j < 64; ++j) { S.pref[j] = run; run += S.cnt[j]; }
  }
  if (t < 64) S.cur[t] = 0;
  __syncthreads();
  for (int i = t; i < c; i += 256) {
    uint p = S.sp[i];
    int n = p >> 17;
    int pos = atomicAdd(&S.cur[n], 1);
    S.so[S.pref[n] + pos] = min(p & 0x1FFFF, (uint)(N_NODES - 1));
  }
  __syncthreads();
  for (int i = t; i < c; i += 256) srcs[(size_t)bk * BCAP + i] = S.so[i];
  if (t < 64) {
    int base = bk * BCAP;
    nbeg[bk * 64 + t] = base + S.pref[t];
    nend[bk * 64 + t] = base + S.pref[t] + S.cnt[t];
  }
}

// ---------------- gemm body: fused bf16 MFMA GEMM (pair / pool) ----------------
template <bool CVT, bool RES, bool SECOND, bool POOL>
__device__ __forceinline__ void gemm2_body(GemmSh& S, int row0, int t,
    const ushort* __restrict__ Ab, const float* __restrict__ Af,
    const ushort* __restrict__ W1, const float* __restrict__ b1,
    const ushort* __restrict__ res, ushort* __restrict__ out1,
    const ushort* __restrict__ W2, const float* __restrict__ b2,
    ushort* __restrict__ out2,
    const int* __restrict__ batch, float* __restrict__ g) {
  const int lane = t & 63;
  const int col0 = (t >> 6) * 32;
  const int lr = lane & 15, lk = (lane >> 4) * 8;

  // W1 fragments -> registers (L2-broadcast)
  bf16x8 bfr[4][2];
  #pragma unroll
  for (int kk = 0; kk < 4; ++kk) {
    bfr[kk][0] = *(const bf16x8*)&W1[(col0 + lr) * 128 + kk * 32 + lk];
    bfr[kk][1] = *(const bf16x8*)&W1[(col0 + 16 + lr) * 128 + kk * 32 + lk];
  }

  #pragma unroll
  for (int i = 0; i < 4; ++i) {            // A tile: 64 x 128
    int c = t + 256 * i;
    int r = c >> 4, k8 = (c & 15) * 8;
    int gr = min(row0 + r, N_NODES - 1);
    if (CVT) {
      const float* src = &Af[(size_t)gr * 128 + k8];
      float4 x0 = *(const float4*)src;
      float4 x1 = *(const float4*)(src + 4);
      uint4v u;
      u.x = pk2(x0.x, x0.y); u.y = pk2(x0.z, x0.w);
      u.z = pk2(x1.x, x1.y); u.w = pk2(x1.z, x1.w);
      *(uint4v*)&S.sA[r][k8] = u;
    } else {
      *(uint4*)&S.sA[r][k8] = *(const uint4*)&Ab[(size_t)gr * 128 + k8];
    }
  }
  __syncthreads();

  f32x4 acc[4][2] = {};
  #pragma unroll
  for (int kk = 0; kk < 4; ++kk) {
    int kb = kk * 32 + lk;
    #pragma unroll
    for (int m = 0; m < 4; ++m) {
      bf16x8 a = *(const bf16x8*)&S.sA[m * 16 + lr][kb];
      acc[m][0] = __builtin_amdgcn_mfma_f32_16x16x32_bf16(a, bfr[kk][0], acc[m][0], 0, 0, 0);
      acc[m][1] = __builtin_amdgcn_mfma_f32_16x16x32_bf16(a, bfr[kk][1], acc[m][1], 0, 0, 0);
    }
  }

  // W2 fragments (issued while waiting on the barrier)
  bf16x8 bfr2[4][2];
  if (SECOND) {
    #pragma unroll
    for (int kk = 0; kk < 4; ++kk) {
      bfr2[kk][0] = *(const bf16x8*)&W2[(col0 + lr) * 128 + kk * 32 + lk];
      bfr2[kk][1] = *(const bf16x8*)&W2[(col0 + 16 + lr) * 128 + kk * 32 + lk];
    }
  }
  __syncthreads();   // all sA reads done before stash

  const int rb = (lane >> 4) * 4;   // C/D: row=(lane>>4)*4+j, col=lane&15
  #pragma unroll
  for (int n = 0; n < 2; ++n) {
    int col = col0 + n * 16 + lr;
    float bv = b1[col];
    #pragma unroll
    for (int m = 0; m < 4; ++m) {
      #pragma unroll
      for (int j = 0; j < 4; ++j) {
        int r = row0 + m * 16 + rb + j;
        float v = fmaxf(acc[m][n][j] + bv, 0.f);
        if (RES && r < N_NODES) v += bf2f(res[(size_t)r * 128 + col]);
        S.sA[m * 16 + rb + j][col] = f2bf(v);
      }
    }
  }
  if (POOL && t < 64)
    S.sb[t] = (row0 + t < N_NODES) ? batch[row0 + t] : -1;
  __syncthreads();

  if (POOL) {
    // column-scan pooling: thread handles col (t&127), rows [half*32, +32)
    int c = t & 127, half = t >> 7;
    int v0 = half * 32, v1 = v0 + 32;
    int cur = S.sb[v0];
    if (cur >= 0) {
      float acc2 = 0.f;
      for (int v = v0; v < v1; ++v) {
        int b = S.sb[v];
        if (b < 0) break;
        if (b != cur) {
          unsafeAtomicAdd(&g[cur * 128 + c], acc2);
          acc2 = 0.f;
          cur = b;
        }
        acc2 += bf2f(S.sA[v][c]);
      }
      unsafeAtomicAdd(&g[cur * 128 + c], acc2);
    }
    return;
  }

  #pragma unroll
  for (int i = 0; i < 4; ++i) {            // coalesced 16B stores of C1
    int c = t + 256 * i;
    int r = c >> 4, k8 = (c & 15) * 8;
    int gr = row0 + r;
    if (gr < N_NODES)
      *(uint4*)&out1[(size_t)gr * 128 + k8] = *(const uint4*)&S.sA[r][k8];
  }

  if (SECOND) {
    // second GEMM: A-operand = stashed C1 (read-only on sA, no barrier vs stores)
    f32x4 acc2[4][2] = {};
    #pragma unroll
    for (int kk = 0; kk < 4; ++kk) {
      int kb = kk * 32 + lk;
      #pragma unroll
      for (int m = 0; m < 4; ++m) {
        bf16x8 a = *(const bf16x8*)&S.sA[m * 16 + lr][kb];
        acc2[m][0] = __builtin_amdgcn_mfma_f32_16x16x32_bf16(a, bfr2[kk][0], acc2[m][0], 0, 0, 0);
        acc2[m][1] = __builtin_amdgcn_mfma_f32_16x16x32_bf16(a, bfr2[kk][1], acc2[m][1], 0, 0, 0);
      }
    }
    __syncthreads();   // MFMA2 reads + C1 stores done before re-stash

    #pragma unroll
    for (int n = 0; n < 2; ++n) {
      int col = col0 + n * 16 + lr;
      float bv = b2[col];
      #pragma unroll
      for (int m = 0; m < 4; ++m) {
        #pragma unroll
        for (int j = 0; j < 4; ++j) {
          float v = fmaxf(acc2[m][n][j] + bv, 0.f);
          S.sA[m * 16 + rb + j][col] = f2bf(v);
        }
      }
    }
    __syncthreads();

    #pragma unroll
    for (int i = 0; i < 4; ++i) {          // coalesced 16B stores of C2
      int c = t + 256 * i;
      int r = c >> 4, k8 = (c & 15) * 8;
      int gr = row0 + r;
      if (gr < N_NODES)
        *(uint4*)&out2[(size_t)gr * 128 + k8] = *(const uint4*)&S.sA[r][k8];
    }
  }
}

// ---------------- fat kernel A: bucket binning ∥ weight prep ----------------
// blocks [0,NFB): two-pass block-claimed binning (1024 thr, 16 waves — R18
// showed latency-bound at low occupancy). blocks [NFB,NFB+7): fp32->bf16
// transposed weight prep (independent work, rides free).
__global__ __launch_bounds__(1024) void k_bfill_prep(const int* __restrict__ e32,
    const long long* __restrict__ e64, int* __restrict__ bcur,
    uint* __restrict__ packed,
    const float* __restrict__ W_in, const float* __restrict__ W_msg,
    const float* __restrict__ W_upd, ushort* __restrict__ Wt) {
  __shared__ int lcnt[NB];
  __shared__ int lbase[NB];
  __shared__ int sflag;
  const int t = threadIdx.x;

  if (blockIdx.x >= NFB) {   // weight prep
    int b = blockIdx.x - NFB;  // 0: in, 1..3: msg[l], 4..6: upd[l]
    const float* W = (b == 0) ? W_in : (b <= 3 ? W_msg + (size_t)(b - 1) * 16384
                                               : W_upd + (size_t)(b - 4) * 16384);
    ushort* O = Wt + (size_t)b * 16384;
    for (int i = t; i < 16384; i += 1024) {
      int k = i >> 7, c = i & 127;
      O[c * 128 + k] = f2bf(W[i]);
    }
    return;
  }

  const int e0 = blockIdx.x * (N_EDGES / NFB);   // 6250 per block
  const int e1 = e0 + (N_EDGES / NFB);
  for (int k = t; k < NB; k += 1024) lcnt[k] = 0;
  if (t == 0) {
    int any = 0;
    for (int i = 1; i < 128; i += 2) any |= e32[i];
    sflag = (any == 0) ? 1 : 0;
  }
  __syncthreads();
  const bool f64 = (sflag != 0);
  if (f64) {
    for (int i = e0 + t; i < e1; i += 1024)
      atomicAdd(&lcnt[((int)e64[N_EDGES + i]) >> 6], 1);
  } else {
    for (int i = e0 + t; i < e1; i += 1024)
      atomicAdd(&lcnt[e32[N_EDGES + i] >> 6], 1);
  }
  __syncthreads();
  for (int k = t; k < NB; k += 1024) {
    int c = lcnt[k];
    lbase[k] = (c > 0) ? atomicAdd(&bcur[k * 16], c) : 0;  // padded counters
    lcnt[k] = 0;   // reuse as cursor
  }
  __syncthreads();
  for (int i = e0 + t; i < e1; i += 1024) {
    int d, s;
    if (f64) { d = (int)e64[N_EDGES + i]; s = (int)e64[i]; }
    else     { d = e32[N_EDGES + i];      s = e32[i]; }
    int bk = d >> 6;
    int pos = lbase[bk] + atomicAdd(&lcnt[bk], 1);
    if (pos < BCAP)
      packed[(size_t)bk * BCAP + pos] = ((uint)(d & 63) << 17) | (uint)s;
  }
}

// ---------------- fat kernel B: bucket sort ∥ input GEMM pair ----------------
// blocks [0,NB): counting sort. blocks [NB,2*NB): h0 = relu(x@W_in+b_in),
// msg0 = relu(h0@Wm0+bm0). Independent (sort consumes packed; gemm consumes
// x/Wt) — overlapping hides the whole sort under the GEMM.
__global__ __launch_bounds__(256) void k_bsort_gemm(const int* __restrict__ bcur,
    const uint* __restrict__ packed, uint* __restrict__ srcs,
    int* __restrict__ nbeg, int* __restrict__ nend,
    const float* __restrict__ x, const ushort* __restrict__ Wt,
    const float* __restrict__ b_in, ushort* __restrict__ h0,
    const ushort* __restrict__ Wm0, const float* __restrict__ bm0,
    ushort* __restrict__ msg0) {
  __shared__ FatSh sh;
  if (blockIdx.x < NB) {
    bsort_body(sh.b, blockIdx.x, threadIdx.x, bcur, packed, srcs, nbeg, nend);
  } else {
    gemm2_body<true, false, true, false>(sh.g, (blockIdx.x - NB) * 64,
        threadIdx.x, nullptr, x, Wt, b_in, nullptr, h0, Wm0, bm0, msg0,
        nullptr, nullptr);
  }
}

// ---------------- standalone gemm kernel (layer loop) ----------------
template <bool CVT, bool RES, bool SECOND, bool POOL>
__global__ __launch_bounds__(256) void k_gemm2(const ushort* __restrict__ Ab,
    const float* __restrict__ Af,
    const ushort* __restrict__ W1, const float* __restrict__ b1,
    const ushort* __restrict__ res, ushort* __restrict__ out1,
    const ushort* __restrict__ W2, const float* __restrict__ b2,
    ushort* __restrict__ out2,
    const int* __restrict__ batch, float* __restrict__ g) {
  __shared__ GemmSh sh;
  gemm2_body<CVT, RES, SECOND, POOL>(sh, blockIdx.x * 64, threadIdx.x,
      Ab, Af, W1, b1, res, out1, W2, b2, out2, batch, g);
}

// ---------------- aggregation: one wave per node, 16 edges in flight ----------------
__global__ __launch_bounds__(256) void k_aggregate(const int* __restrict__ nbeg,
    const int* __restrict__ nend, const uint* __restrict__ srcs,
    const ushort* __restrict__ msg, ushort* __restrict__ agg) {
  int wid = blockIdx.x * 4 + (threadIdx.x >> 6);
  if (wid >= N_NODES) return;
  const int lane = threadIdx.x & 63;
  const uint sub = lane >> 4, l16 = lane & 15;
  int e = nbeg[wid];
  const int en = nend[wid];
  float a[8] = {0.f, 0.f, 0.f, 0.f, 0.f, 0.f, 0.f, 0.f};

#define ACC8(mv)                                              \
  a[0] += bf2f((ushort)mv.x); a[1] += bf2f((ushort)(mv.x >> 16)); \
  a[2] += bf2f((ushort)mv.y); a[3] += bf2f((ushort)(mv.y >> 16)); \
  a[4] += bf2f((ushort)mv.z); a[5] += bf2f((ushort)(mv.z >> 16)); \
  a[6] += bf2f((ushort)mv.w); a[7] += bf2f((ushort)(mv.w >> 16));

  for (; e + 16 <= en; e += 16) {
    uint s0 = srcs[e + sub];
    uint s1 = srcs[e + 4 + sub];
    uint s2 = srcs[e + 8 + sub];
    uint s3 = srcs[e + 12 + sub];
    uint4 m0 = *(const uint4*)&msg[s0 * 128u + l16 * 8u];
    uint4 m1 = *(const uint4*)&msg[s1 * 128u + l16 * 8u];
    uint4 m2 = *(const uint4*)&msg[s2 * 128u + l16 * 8u];
    uint4 m3 = *(const uint4*)&msg[s3 * 128u + l16 * 8u];
    ACC8(m0) ACC8(m1) ACC8(m2) ACC8(m3)
  }
  const uint rem = (uint)(en - e);   // 0..15
  #pragma unroll
  for (uint k = 0; k < 4; ++k) {
    uint idx = k * 4 + sub;
    if (idx < rem) {
      uint s = srcs[e + idx];
      uint4 m = *(const uint4*)&msg[s * 128u + l16 * 8u];
      ACC8(m)
    }
  }
#undef ACC8

  #pragma unroll
  for (int j = 0; j < 8; ++j) {
    a[j] += __shfl_xor(a[j], 16, 64);
    a[j] += __shfl_xor(a[j], 32, 64);
  }
  if (sub == 0) {
    uint4 r;
    r.x = pk2(a[0], a[1]);
    r.y = pk2(a[2], a[3]);
    r.z = pk2(a[4], a[5]);
    r.w = pk2(a[6], a[7]);
    *(uint4*)&agg[(size_t)wid * 128 + l16 * 8] = r;
  }
}

// ---------------- output heads (fp32) ----------------
__global__ __launch_bounds__(128) void k_head(const float* __restrict__ g,
    const float* __restrict__ Wm, const float* __restrict__ bm,
    const float* __restrict__ Wl, const float* __restrict__ bl,
    float* __restrict__ out) {
  __shared__ float sg[128];
  int gr = blockIdx.x, t = threadIdx.x;
  sg[t] = g[gr * 128 + t];
  __syncthreads();
  const float* W = (t < 64) ? Wm : Wl;
  const float* b = (t < 64) ? bm : bl;
  int c = t & 63;
  float acc = b[c];
  #pragma unroll 8
  for (int k = 0; k < 128; ++k) acc += sg[k] * W[k * 64 + c];
  out[(size_t)(t < 64 ? 0 : N_GRAPHS * 64) + (size_t)gr * 64 + c] = acc;
}

// ---------------- host ----------------
extern "C" void kernel_launch(void* const* d_in, const int* in_sizes, int n_in,
                              void* d_out, int out_size, void* d_ws, size_t ws_size,
                              hipStream_t stream) {
  const float* x      = (const float*)d_in[0];
  const int* e32      = (const int*)d_in[1];
  const long long* e64 = (const long long*)d_in[1];
  const int* batch    = (const int*)d_in[2];
  const float* W_in   = (const float*)d_in[3];
  const float* b_in   = (const float*)d_in[4];
  const float* W_msg  = (const float*)d_in[5];
  const float* b_msg  = (const float*)d_in[6];
  const float* W_upd  = (const float*)d_in[7];
  const float* b_upd  = (const float*)d_in[8];
  const float* W_mean = (const float*)d_in[9];
  const float* b_mean = (const float*)d_in[10];
  const float* W_lv   = (const float*)d_in[11];
  const float* b_lv   = (const float*)d_in[12];
  float* out = (float*)d_out;

  char* p = (char*)d_ws;
  auto alloc = [&](size_t bytes) {
    char* r = p;
    p += (bytes + 255) & ~(size_t)255;
    return r;
  };
  ushort* bufA   = (ushort*)alloc((size_t)N_NODES * 128 * 2);
  ushort* bufB   = (ushort*)alloc((size_t)N_NODES * 128 * 2);
  ushort* bufC   = (ushort*)alloc((size_t)N_NODES * 128 * 2);
  ushort* bufM   = (ushort*)alloc((size_t)N_NODES * 128 * 2);
  ushort* Wt     = (ushort*)alloc((size_t)7 * 16384 * 2);
  uint*   packed = (uint*)alloc((size_t)NB * BCAP * 4);
  uint*   srcs   = (uint*)alloc((size_t)NB * BCAP * 4);
  int*    bcur   = (int*)alloc((size_t)NB * 16 * 4);
  int*    nbeg   = (int*)alloc((size_t)NB * 64 * 4);
  int*    nend   = (int*)alloc((size_t)NB * 64 * 4);
  float*  g      = (float*)alloc((size_t)N_GRAPHS * 128 * 4);

  hipMemsetAsync(bcur, 0, (size_t)NB * 16 * 4, stream);
  hipMemsetAsync(g, 0, (size_t)N_GRAPHS * 128 * 4, stream);

  const ushort* Wm[3] = {Wt + 16384, Wt + 2 * 16384, Wt + 3 * 16384};
  const ushort* Wu[3] = {Wt + 4 * 16384, Wt + 5 * 16384, Wt + 6 * 16384};

  // fat A: bucket binning ∥ weight prep
  k_bfill_prep<<<NFB + 7, 1024, 0, stream>>>(e32, e64, bcur, packed,
                                             W_in, W_msg, W_upd, Wt);

  // fat B: bucket sort ∥ (h0 = relu(x@W_in+b_in) ; msg0 = relu(h0@Wm0+bm0))
  k_bsort_gemm<<<2 * NB, 256, 0, stream>>>(bcur, packed, srcs, nbeg, nend,
                                           x, Wt, b_in, bufA, Wm[0], b_msg, bufM);

  ushort* h = bufA;
  ushort* hn = bufB;
  for (int l = 0; l < N_LAYERS; ++l) {
    k_aggregate<<<(N_NODES + 3) / 4, 256, 0, stream>>>(nbeg, nend, srcs, bufM, bufC);
    if (l < N_LAYERS - 1) {
      // fused: hn = relu(agg@Wu+bu)+h ; msg_{l+1} = relu(hn@Wm+bm)
      k_gemm2<false, true, true, false><<<NB, 256, 0, stream>>>(
          bufC, nullptr, Wu[l], b_upd + (size_t)l * 128, h, hn,
          Wm[l + 1], b_msg + (size_t)(l + 1) * 128, bufM, nullptr, nullptr);
      ushort* sw = h; h = hn; hn = sw;
    } else {
      // last layer: pool fused, h3 never hits global memory
      k_gemm2<false, true, false, true><<<NB, 256, 0, stream>>>(
          bufC, nullptr, Wu[l], b_upd + (size_t)l * 128, h, nullptr,
          nullptr, nullptr, nullptr, batch, g);
    }
  }

  // heads
  k_head<<<N_GRAPHS, 128, 0, stream>>>(g, W_mean, b_mean, W_lv, b_lv, out);
}